// Round 17
// baseline (156.531 us; speedup 1.0000x reference)
//
#include <hip/hip_runtime.h>

#define B_ROWS 2048
#define N_GLB  65536
#define DDIM   128
#define NCLUST 100
#define INV_T  (1.0f/0.07f)
#define LOG2E  1.4426950408889634f
#define LN2    0.6931471805599453f
#define NSPLIT 32
#define CHUNK_COLS (N_GLB/NSPLIT)   // 2048 cols per chunk (256 KB fp8, 4 chunks/XCD)
#define ITERS (CHUNK_COLS/64)       // 32 iters, 64 cols per block-iter (16/wave)
#define ROWSB 32                    // f-rows per block (grid 2048 -> 8 waves/SIMD)
#define GRPB 2048                   // bytes per 16-row fp8 fragment group
#define TOPK 10
#define CAP  256
#define NSLICE 8                    // csum flush slices
#define TAU_L2E (3.7881f*LOG2E)     // 3.0 sigma threshold, in log2e units
#define CSC    65536.0f             // csum fixed-point scale 2^16
#define INV_CSC (1.0f/65536.0f)
#define ZWORDS 105472               // zero-region words (csum+hist8+cnt)

typedef __attribute__((ext_vector_type(4))) float f32x4;
typedef __attribute__((ext_vector_type(2))) long lg2;   // 2 x i64 fp8 fragments
typedef unsigned long long u64;

__device__ __forceinline__ unsigned fmono(float v) {  // order-preserving f32->u32
  unsigned u = __float_as_uint(v);
  return ((int)u < 0) ? ~u : (u | 0x80000000u);
}
__device__ __forceinline__ float fmono_inv(unsigned m) {
  unsigned u = (m & 0x80000000u) ? (m & 0x7FFFFFFFu) : ~m;
  return __uint_as_float(u);
}
__device__ __forceinline__ u64 mkkey(float val, int col) {
  return ((u64)fmono(val) << 32) | (unsigned)(~(unsigned)col);
}
__device__ __forceinline__ u64 umax64(u64 a, u64 b) { return a > b ? a : b; }

// OCP e4m3 decode (fallback path only)
__device__ __forceinline__ float fp8d(unsigned b) {
  unsigned e = (b >> 3) & 15, m = b & 7;
  float v = e ? __uint_as_float(((e + 120u) << 23) | (m << 20))
              : (float)m * 0.001953125f;   // subnormal: m * 2^-9
  return (b & 0x80u) ? -v : v;
}

// ---- prep: normalize, fp8-e4m3 convert, fragment layout via LDS ----
// fp8 frag layout (mfma_f32_16x16x32_fp8_fp8, A/B = i64 per K=32 slice):
// row r, dim k: byte = (r>>4)*2048 + (k>>6)*1024 + ((k>>3)&3)*256
//                      + (r&15)*16 + ((k>>5)&1)*8 + (k&7)
// f-blocks also zero the accumulator region (replaces hipMemsetAsync).
__global__ __launch_bounds__(256) void prep_kernel(
    const float* __restrict__ f, const float* __restrict__ g,
    char* __restrict__ wsf2, char* __restrict__ wsg2,
    float* __restrict__ inv_fT, float* __restrict__ inv_g,
    unsigned* __restrict__ zbase) {
  __shared__ unsigned short lds[1024];    // 2KB fragment group
  const int t = threadIdx.x, lane = t & 63, w = t >> 6;
  const int grp = blockIdx.x;             // f groups 0..127, then g groups
  const bool isf = grp < (B_ROWS / 16);

  if (isf) {
    int gid = grp * 256 + t;
    #pragma unroll
    for (int k = 0; k < 4; ++k) {
      int idx = gid + k * 32768;
      if (idx < ZWORDS) zbase[idx] = 0u;
    }
  }

  #pragma unroll
  for (int j = 0; j < 4; ++j) {
    int rit = w * 4 + j;                  // row in group
    int row = grp * 16 + rit;
    int rr = isf ? row : row - B_ROWS;
    const float* src = (isf ? f : g) + (size_t)rr * DDIM;
    float2 v = ((const float2*)src)[lane];   // dims 2*lane, 2*lane+1
    float ss = v.x * v.x + v.y * v.y;
    #pragma unroll
    for (int m = 32; m; m >>= 1) ss += __shfl_xor(ss, m);
    float inv = 1.0f / fmaxf(sqrtf(ss), 1e-12f);
    if (lane == 0) { if (isf) inv_fT[rr] = inv * INV_T; else inv_g[rr] = inv; }
    float sc = isf ? inv * (INV_T * LOG2E) : inv;   // fold 1/T and log2e into f
    unsigned pk = __builtin_amdgcn_cvt_pk_fp8_f32(v.x * sc, v.y * sc, 0u, false);
    int k = 2 * lane;
    int off = ((k >> 6) << 10) + (((k >> 3) & 3) << 8) + (rit << 4)
            + (((k >> 5) & 1) << 3) + (k & 7);      // even (k even)
    lds[off >> 1] = (unsigned short)(pk & 0xFFFFu);
  }
  __syncthreads();
  char* dst = isf ? (wsf2 + (size_t)grp * GRPB)
                  : (wsg2 + (size_t)(grp - B_ROWS / 16) * GRPB);
  if (t < 128) ((uint4*)dst)[t] = ((const uint4*)lds)[t];
}

// ---- csum2: cluster sums from fp32 g (coalesced stream), 256 blocks ----
// LDS int accumulate (deterministic: per-elem quantize + commutative int adds),
// sliced global-atomic flush.
__global__ __launch_bounds__(256) void csum2_kernel(
    const float* __restrict__ g, const int* __restrict__ gclust,
    const float* __restrict__ inv_g,
    int* __restrict__ csum_i32, int* __restrict__ hist8) {
  __shared__ int cs[NCLUST * DDIM];   // 51.2 KB
  __shared__ int hcnt[NCLUST];
  const int t = threadIdx.x, lane = t & 63, w = t >> 6;
  for (int i = t; i < NCLUST * DDIM; i += 256) cs[i] = 0;
  if (t < NCLUST) hcnt[t] = 0;
  __syncthreads();

  const int rbase = blockIdx.x * 256;
  const int rg = lane >> 4;            // row subgroup 0..3
  const int ch = lane & 15;            // dims 8*ch .. 8*ch+7
  for (int step = 0; step < 16; ++step) {
    int row = rbase + step * 16 + w * 4 + rg;
    int c = gclust[row];
    float scale = inv_g[row] * CSC;
    const float* gp = g + (size_t)row * DDIM + 8 * ch;
    float4 a = *(const float4*)gp;
    float4 b = *(const float4*)(gp + 4);
    int* dst = &cs[c * DDIM + ch * 8];
    atomicAdd(dst + 0, (int)rintf(a.x * scale));
    atomicAdd(dst + 1, (int)rintf(a.y * scale));
    atomicAdd(dst + 2, (int)rintf(a.z * scale));
    atomicAdd(dst + 3, (int)rintf(a.w * scale));
    atomicAdd(dst + 4, (int)rintf(b.x * scale));
    atomicAdd(dst + 5, (int)rintf(b.y * scale));
    atomicAdd(dst + 6, (int)rintf(b.z * scale));
    atomicAdd(dst + 7, (int)rintf(b.w * scale));
    if (ch == 0) atomicAdd(&hcnt[c], 1);
  }
  __syncthreads();
  const int slice = blockIdx.x & (NSLICE - 1);
  for (int i = t; i < NCLUST * DDIM; i += 256) {
    int x = cs[i];
    if (x) atomicAdd(&csum_i32[(size_t)slice * NCLUST * DDIM + i], x);
  }
  if (t < NCLUST && hcnt[t]) atomicAdd(&hist8[slice * 128 + t], hcnt[t]);
}

// ---- sim: no-LDS fp8 MFMA GEMM, 32 rows/block, 8 waves/SIMD, 256KB chunks ----
#define PUSHQ(av, mm, q)                                                        \
  if ((av) > TAU_L2E) {                                                         \
    int rw = r0 + (mm) * 16 + lhi * 4 + (q);                                    \
    int slot = atomicAdd(&cnt[rw], 1);                                          \
    if (slot < CAP) { lv[rw * CAP + slot] = (av) * LN2; li[rw * CAP + slot] = colv; } \
  }

#define EPI(a, mm)                                                              \
  {                                                                             \
    se[mm].x += __builtin_amdgcn_exp2f(a.x);                                    \
    se[mm].y += __builtin_amdgcn_exp2f(a.y);                                    \
    se[mm].z += __builtin_amdgcn_exp2f(a.z);                                    \
    se[mm].w += __builtin_amdgcn_exp2f(a.w);                                    \
    float mx = fmaxf(fmaxf(a.x, a.y), fmaxf(a.z, a.w));                         \
    if (mx > TAU_L2E) { PUSHQ(a.x, mm, 0) PUSHQ(a.y, mm, 1) PUSHQ(a.z, mm, 2) PUSHQ(a.w, mm, 3) } \
  }

#define LOADB(dst, gptr)                                                        \
  { dst[0] = *(const uint4*)((gptr) + (size_t)lane * 16);                       \
    dst[1] = *(const uint4*)((gptr) + 1024 + (size_t)lane * 16); }

// consume bb (iter itv) while refilling bb in-place for iter itv+2;
// two independent single-chain accumulators (one per 16-row group)
#define COMPUTE_REFILL(bb, itv, refbase, dorefill)                              \
  {                                                                             \
    f32x4 ac0 = {0,0,0,0}, ac1 = {0,0,0,0};                                     \
    lg2 bs0 = __builtin_bit_cast(lg2, bb[0]);                                   \
    lg2 bs1 = __builtin_bit_cast(lg2, bb[1]);                                   \
    if (dorefill) {                                                             \
      bb[0] = *(const uint4*)((refbase) + (size_t)lane * 16);                   \
      bb[1] = *(const uint4*)((refbase) + 1024 + (size_t)lane * 16);            \
    }                                                                           \
    ac0 = __builtin_amdgcn_mfma_f32_16x16x32_fp8_fp8(afr[0][0][0], bs0[0], ac0, 0, 0, 0); \
    ac1 = __builtin_amdgcn_mfma_f32_16x16x32_fp8_fp8(afr[1][0][0], bs0[0], ac1, 0, 0, 0); \
    ac0 = __builtin_amdgcn_mfma_f32_16x16x32_fp8_fp8(afr[0][0][1], bs0[1], ac0, 0, 0, 0); \
    ac1 = __builtin_amdgcn_mfma_f32_16x16x32_fp8_fp8(afr[1][0][1], bs0[1], ac1, 0, 0, 0); \
    ac0 = __builtin_amdgcn_mfma_f32_16x16x32_fp8_fp8(afr[0][1][0], bs1[0], ac0, 0, 0, 0); \
    ac1 = __builtin_amdgcn_mfma_f32_16x16x32_fp8_fp8(afr[1][1][0], bs1[0], ac1, 0, 0, 0); \
    ac0 = __builtin_amdgcn_mfma_f32_16x16x32_fp8_fp8(afr[0][1][1], bs1[1], ac0, 0, 0, 0); \
    ac1 = __builtin_amdgcn_mfma_f32_16x16x32_fp8_fp8(afr[1][1][1], bs1[1], ac1, 0, 0, 0); \
    const int colv = chunk * CHUNK_COLS + (itv) * 64 + w * 16 + l15;            \
    EPI(ac0, 0) EPI(ac1, 1)                                                     \
  }

__global__ __launch_bounds__(256, 8) void sim_kernel(
    const char* __restrict__ wsf2, const char* __restrict__ wsg2,
    float* __restrict__ p_se, float* __restrict__ lv, int* __restrict__ li,
    int* __restrict__ cnt) {
  __shared__ float sered[4][ROWSB];
  const int t = threadIdx.x, lane = t & 63, w = t >> 6;
  const int l15 = lane & 15, lhi = lane >> 4;
  const int chunk = blockIdx.x;          // 0..31 (chunk%8 -> XCD pinned)
  const int r0 = blockIdx.y * ROWSB;

  // hoist A fragments: 32 f-rows x 128 K in regs (16 VGPR)
  const char* fbase = wsf2 + (size_t)(r0 >> 4) * GRPB;
  lg2 afr[2][2];
  #pragma unroll
  for (int m = 0; m < 2; ++m)
    #pragma unroll
    for (int sp = 0; sp < 2; ++sp)
      afr[m][sp] = __builtin_bit_cast(lg2,
        *(const uint4*)(fbase + (size_t)m * GRPB + sp * 1024 + (size_t)lane * 16));

  f32x4 z = {0.f, 0.f, 0.f, 0.f};
  f32x4 se[2] = {z, z};

  // wave w's 16-col group for iter it lives at (it*4 + w)*GRPB within the chunk
  const char* gb = wsg2 + (size_t)(chunk * (CHUNK_COLS / 16) + w) * GRPB;
  uint4 b0[2], b1[2];
  LOADB(b0, gb)                          // it+0
  LOADB(b1, gb + 4 * GRPB)               // it+1
  for (int it = 0; it < ITERS; it += 2) {
    COMPUTE_REFILL(b0, it,     gb + 8 * GRPB,  it + 2 < ITERS)   // -> it+2
    COMPUTE_REFILL(b1, it + 1, gb + 12 * GRPB, it + 3 < ITERS)   // -> it+3
    gb += 8 * GRPB;
  }

  #pragma unroll
  for (int m = 0; m < 2; ++m)
    #pragma unroll
    for (int q = 0; q < 4; ++q) {
      float s = se[m][q];
      s += __shfl_xor(s, 1); s += __shfl_xor(s, 2);
      s += __shfl_xor(s, 4); s += __shfl_xor(s, 8);
      if (l15 == 0) sered[w][m * 16 + lhi * 4 + q] = s;
    }
  __syncthreads();
  if (t < ROWSB) {
    float s = sered[0][t] + sered[1][t] + sered[2][t] + sered[3][t];
    p_se[(size_t)(r0 + t) * NSPLIT + chunk] = s;
  }
}

// ---- merge (+inline fallback): per-row se, cluster dot, exact top-10 ----
__global__ __launch_bounds__(256) void merge_kernel(
    const float* __restrict__ f, const int* __restrict__ fclust,
    const int* __restrict__ gclust, const float* __restrict__ inv_fT,
    const float* __restrict__ p_se, const int* __restrict__ csum_i32,
    const int* __restrict__ hist8, const float* __restrict__ lv,
    const int* __restrict__ li, const int* __restrict__ cnt,
    const char* __restrict__ wsf2, const char* __restrict__ wsg2,
    float* __restrict__ rowv) {
  const int lane = threadIdx.x & 63, w = threadIdx.x >> 6;
  const int r = blockIdx.x * 4 + w;

  float sev = (lane < NSPLIT) ? p_se[(size_t)r * NSPLIT + lane] : 0.f;
  sev += __shfl_xor(sev, 16); sev += __shfl_xor(sev, 8);
  sev += __shfl_xor(sev, 4);  sev += __shfl_xor(sev, 2);
  sev += __shfl_xor(sev, 1);
  sev = __shfl(sev, 0);

  int rc = fclust[r];
  float2 fv = ((const float2*)(f + (size_t)r * DDIM))[lane];
  float sc = inv_fT[r];
  int ia = 0, ib = 0, hc = 0;
  #pragma unroll
  for (int s = 0; s < NSLICE; ++s) {
    ia += csum_i32[(size_t)s * NCLUST * DDIM + rc * DDIM + 2 * lane];
    ib += csum_i32[(size_t)s * NCLUST * DDIM + rc * DDIM + 2 * lane + 1];
    hc += hist8[s * 128 + rc];
  }
  float dt = fv.x * sc * (ia * INV_CSC) + fv.y * sc * (ib * INV_CSC);
  #pragma unroll
  for (int m = 32; m; m >>= 1) dt += __shfl_xor(dt, m);
  dt = __shfl(dt, 0);

  float Cc = (float)hc;
  int n = cnt[r];
  bool bad = (n < TOPK) || (n > CAP);
  float S10 = 0.f, C10 = 0.f;
  if (!bad) {
    u64 k0 = 0, k1 = 0, k2 = 0, k3 = 0;
    int e = lane;
    if (e < n) k0 = mkkey(lv[(size_t)r * CAP + e], li[(size_t)r * CAP + e]);
    e = lane + 64;
    if (e < n) k1 = mkkey(lv[(size_t)r * CAP + e], li[(size_t)r * CAP + e]);
    e = lane + 128;
    if (e < n) k2 = mkkey(lv[(size_t)r * CAP + e], li[(size_t)r * CAP + e]);
    e = lane + 192;
    if (e < n) k3 = mkkey(lv[(size_t)r * CAP + e], li[(size_t)r * CAP + e]);
    for (int it = 0; it < TOPK; ++it) {
      u64 best = umax64(umax64(k0, k1), umax64(k2, k3));
      #pragma unroll
      for (int m = 32; m; m >>= 1) best = umax64(best, __shfl_xor(best, m));
      float val = fmono_inv((unsigned)(best >> 32));
      int col = (int)(~(unsigned)(best & 0xFFFFFFFFull));
      int gc = gclust[col];
      if (gc != rc) { S10 += val; C10 += 1.f; }
      if (k0 == best) k0 = 0;
      if (k1 == best) k1 = 0;
      if (k2 == best) k2 = 0;
      if (k3 == best) k3 = 0;
    }
  } else {
    // inline fallback: exact top-10 via full fp8 recompute (rare; correctness net)
    uint4 fr[8];
    #pragma unroll
    for (int pc = 0; pc < 8; ++pc)
      fr[pc] = *(const uint4*)(wsf2 + (size_t)(r >> 4) * GRPB + (pc >> 2) * 1024
                               + (pc & 3) * 256 + (r & 15) * 16);
    u64 tk[TOPK];
    #pragma unroll
    for (int i = 0; i < TOPK; ++i) tk[i] = 0;
    for (int col = lane; col < N_GLB; col += 64) {
      const char* gp = wsg2 + (size_t)(col >> 4) * GRPB + (col & 15) * 16;
      float acc = 0.f;
      #pragma unroll
      for (int pc = 0; pc < 8; ++pc) {
        uint4 gv = *(const uint4*)(gp + (pc >> 2) * 1024 + (pc & 3) * 256);
        uint4 fc = fr[pc];
        #pragma unroll
        for (int wd = 0; wd < 4; ++wd) {
          unsigned fa = (&fc.x)[wd], ga = (&gv.x)[wd];
          #pragma unroll
          for (int b = 0; b < 4; ++b)
            acc += fp8d((fa >> (8 * b)) & 0xFFu) * fp8d((ga >> (8 * b)) & 0xFFu);
        }
      }
      u64 key = mkkey(acc, col);   // acc in log2e units; monotonic ordering ok
      if (key > tk[0]) {
        u64 cur = key;
        #pragma unroll
        for (int i = 0; i < TOPK - 1; ++i) {
          u64 nxt = tk[i + 1];
          u64 lo = cur < nxt ? cur : nxt;
          u64 hi = cur < nxt ? nxt : cur;
          tk[i] = lo; cur = hi;
        }
        tk[TOPK - 1] = cur;
      }
    }
    for (int it = 0; it < TOPK; ++it) {
      u64 best = tk[TOPK - 1];
      #pragma unroll
      for (int m = 32; m; m >>= 1) best = umax64(best, __shfl_xor(best, m));
      float val = fmono_inv((unsigned)(best >> 32)) * LN2;
      int col = (int)(~(unsigned)(best & 0xFFFFFFFFull));
      if (gclust[col] != rc) { S10 += val; C10 += 1.f; }
      if (tk[TOPK - 1] == best) {
        #pragma unroll
        for (int i = TOPK - 1; i > 0; --i) tk[i] = tk[i - 1];
        tk[0] = 0;
      }
    }
  }
  if (lane == 0) {
    float L = logf(sev + 1e-12f);
    float C = Cc + C10;
    rowv[r] = (dt + S10 - C * L) / (C + 1e-12f);
  }
}

__global__ void final_kernel(const float* __restrict__ rowv, float* __restrict__ out) {
  __shared__ float sm[256];
  int t = threadIdx.x;
  float s = 0.f;
  for (int i = t; i < B_ROWS; i += 256) s += rowv[i];
  sm[t] = s;
  __syncthreads();
  for (int o = 128; o; o >>= 1) { if (t < o) sm[t] += sm[t + o]; __syncthreads(); }
  if (t == 0) out[0] = -(sm[0] / (float)B_ROWS);
}

extern "C" void kernel_launch(void* const* d_in, const int* in_sizes, int n_in,
                              void* d_out, int out_size, void* d_ws, size_t ws_size,
                              hipStream_t stream) {
  const float* f  = (const float*)d_in[0];
  const int*   fc = (const int*)  d_in[1];
  const float* g  = (const float*)d_in[2];
  const int*   gc = (const int*)  d_in[3];
  float* out = (float*)d_out;

  char* ws = (char*)d_ws;
  char*  wsf2    = ws;                          // 256 KB fp8 f
  char*  wsg2    = ws + 262144;                 // 8 MB fp8 g -> 8650752
  float* inv_fT  = (float*)(ws + 8650752);      // 8 KB  -> 8658944
  float* inv_g   = (float*)(ws + 8658944);      // 256 KB -> 8921088
  float* p_se    = (float*)(ws + 8921088);      // 2048*32*4 = 256 KB -> 9183232
  // zero region [9183232, 9605120): csum 409600 + hist8 4096 + cnt 8192
  int*   csum_i32= (int*)  (ws + 9183232);      // 409600 -> 9592832
  int*   hist8   = (int*)  (ws + 9592832);      // 4096   -> 9596928
  int*   cnt     = (int*)  (ws + 9596928);      // 8192   -> 9605120
  unsigned* zbase= (unsigned*)(ws + 9183232);   // ZWORDS = 105472 u32 words
  float* lv      = (float*)(ws + 9605120);      // 2 MB -> 11702272
  int*   li      = (int*)  (ws + 11702272);     // 2 MB -> 13799424
  float* rowv    = (float*)(ws + 13799424);     // 8 KB (total ~13.8 MB)

  prep_kernel<<<(B_ROWS + N_GLB) / 16, 256, 0, stream>>>(f, g, wsf2, wsg2,
                                                         inv_fT, inv_g, zbase);

  csum2_kernel<<<N_GLB / 256, 256, 0, stream>>>(g, gc, inv_g, csum_i32, hist8);

  dim3 grid(NSPLIT, B_ROWS / ROWSB);   // 32 x 64 = 2048 blocks (8/CU, 32 waves/CU)
  sim_kernel<<<grid, 256, 0, stream>>>(wsf2, wsg2, p_se, lv, li, cnt);

  merge_kernel<<<B_ROWS / 4, 256, 0, stream>>>(f, fc, gc, inv_fT, p_se, csum_i32,
                                               hist8, lv, li, cnt, wsf2, wsg2, rowv);
  final_kernel<<<1, 256, 0, stream>>>(rowv, out);
}

// Round 19
// 105.812 us; speedup vs baseline: 1.4793x; 1.4793x over previous
//
#include <hip/hip_runtime.h>

#define B_ROWS 2048
#define N_GLB  65536
#define DDIM   128
#define NCLUST 100
#define INV_T  (1.0f/0.07f)
#define LOG2E  1.4426950408889634f
#define LN2    0.6931471805599453f
#define NSPLIT 16
#define CHUNK_COLS (N_GLB/NSPLIT)   // 4096 cols per chunk (512 KB fp8, 2 chunks/XCD)
#define ITERS (CHUNK_COLS/64)       // 64 iters, 64 cols per block-iter (16/wave)
#define ROWSB 16                    // f-rows per block (grid 2048 -> 8 waves/SIMD)
#define GRPB 2048                   // bytes per 16-row fp8 fragment group
#define TOPK 10
#define CAP  256
#define NSLICE 8                    // csum flush slices
#define TAU_L2E (3.7881f*LOG2E)     // 3.0 sigma threshold, in log2e units
#define CSC    65536.0f             // csum fixed-point scale 2^16
#define INV_CSC (1.0f/65536.0f)
#define ZWORDS 105472               // zero-region words (csum+hist8+cnt)

typedef __attribute__((ext_vector_type(4))) float f32x4;
typedef __attribute__((ext_vector_type(2))) long lg2;   // 2 x i64 fp8 fragments
typedef unsigned long long u64;

__device__ __forceinline__ unsigned fmono(float v) {  // order-preserving f32->u32
  unsigned u = __float_as_uint(v);
  return ((int)u < 0) ? ~u : (u | 0x80000000u);
}
__device__ __forceinline__ float fmono_inv(unsigned m) {
  unsigned u = (m & 0x80000000u) ? (m & 0x7FFFFFFFu) : ~m;
  return __uint_as_float(u);
}
__device__ __forceinline__ u64 mkkey(float val, int col) {
  return ((u64)fmono(val) << 32) | (unsigned)(~(unsigned)col);
}
__device__ __forceinline__ u64 umax64(u64 a, u64 b) { return a > b ? a : b; }

// OCP e4m3 decode (fallback path only)
__device__ __forceinline__ float fp8d(unsigned b) {
  unsigned e = (b >> 3) & 15, m = b & 7;
  float v = e ? __uint_as_float(((e + 120u) << 23) | (m << 20))
              : (float)m * 0.001953125f;   // subnormal: m * 2^-9
  return (b & 0x80u) ? -v : v;
}

// ---- prep: normalize, fp8-e4m3 convert, fragment layout via LDS ----
// fp8 frag layout (mfma_f32_16x16x32_fp8_fp8, A/B = i64 per K=32 slice):
// row r, dim k: byte = (r>>4)*2048 + (k>>6)*1024 + ((k>>3)&3)*256
//                      + (r&15)*16 + ((k>>5)&1)*8 + (k&7)
// f-blocks also zero the accumulator region (replaces hipMemsetAsync; stream
// order guarantees visibility to csum2/sim/merge).
__global__ __launch_bounds__(256) void prep_kernel(
    const float* __restrict__ f, const float* __restrict__ g,
    char* __restrict__ wsf2, char* __restrict__ wsg2,
    float* __restrict__ inv_fT, float* __restrict__ inv_g,
    unsigned* __restrict__ zbase) {
  __shared__ unsigned short lds[1024];    // 2KB fragment group
  const int t = threadIdx.x, lane = t & 63, w = t >> 6;
  const int grp = blockIdx.x;             // f groups 0..127, then g groups
  const bool isf = grp < (B_ROWS / 16);

  if (isf) {
    int gid = grp * 256 + t;
    #pragma unroll
    for (int k = 0; k < 4; ++k) {
      int idx = gid + k * 32768;
      if (idx < ZWORDS) zbase[idx] = 0u;
    }
  }

  #pragma unroll
  for (int j = 0; j < 4; ++j) {
    int rit = w * 4 + j;                  // row in group
    int row = grp * 16 + rit;
    int rr = isf ? row : row - B_ROWS;
    const float* src = (isf ? f : g) + (size_t)rr * DDIM;
    float2 v = ((const float2*)src)[lane];   // dims 2*lane, 2*lane+1
    float ss = v.x * v.x + v.y * v.y;
    #pragma unroll
    for (int m = 32; m; m >>= 1) ss += __shfl_xor(ss, m);
    float inv = 1.0f / fmaxf(sqrtf(ss), 1e-12f);
    if (lane == 0) { if (isf) inv_fT[rr] = inv * INV_T; else inv_g[rr] = inv; }
    float sc = isf ? inv * (INV_T * LOG2E) : inv;   // fold 1/T and log2e into f
    unsigned pk = __builtin_amdgcn_cvt_pk_fp8_f32(v.x * sc, v.y * sc, 0u, false);
    int k = 2 * lane;
    int off = ((k >> 6) << 10) + (((k >> 3) & 3) << 8) + (rit << 4)
            + (((k >> 5) & 1) << 3) + (k & 7);      // even (k even)
    lds[off >> 1] = (unsigned short)(pk & 0xFFFFu);
  }
  __syncthreads();
  char* dst = isf ? (wsf2 + (size_t)grp * GRPB)
                  : (wsg2 + (size_t)(grp - B_ROWS / 16) * GRPB);
  ((uint2*)dst)[t] = ((const uint2*)lds)[t];      // all 256 threads, 8B each
}

// ---- csum2: cluster sums from fp32 g (coalesced stream), 256 blocks ----
// LDS int accumulate (deterministic: per-elem quantize + commutative int adds),
// sliced global-atomic flush.
__global__ __launch_bounds__(256) void csum2_kernel(
    const float* __restrict__ g, const int* __restrict__ gclust,
    const float* __restrict__ inv_g,
    int* __restrict__ csum_i32, int* __restrict__ hist8) {
  __shared__ int cs[NCLUST * DDIM];   // 51.2 KB
  __shared__ int hcnt[NCLUST];
  const int t = threadIdx.x, lane = t & 63, w = t >> 6;
  for (int i = t; i < NCLUST * DDIM; i += 256) cs[i] = 0;
  if (t < NCLUST) hcnt[t] = 0;
  __syncthreads();

  const int rbase = blockIdx.x * 256;
  const int rg = lane >> 4;            // row subgroup 0..3
  const int ch = lane & 15;            // dims 8*ch .. 8*ch+7
  for (int step = 0; step < 16; ++step) {
    int row = rbase + step * 16 + w * 4 + rg;
    int c = gclust[row];
    float scale = inv_g[row] * CSC;
    const float* gp = g + (size_t)row * DDIM + 8 * ch;
    float4 a = *(const float4*)gp;
    float4 b = *(const float4*)(gp + 4);
    int* dst = &cs[c * DDIM + ch * 8];
    atomicAdd(dst + 0, (int)rintf(a.x * scale));
    atomicAdd(dst + 1, (int)rintf(a.y * scale));
    atomicAdd(dst + 2, (int)rintf(a.z * scale));
    atomicAdd(dst + 3, (int)rintf(a.w * scale));
    atomicAdd(dst + 4, (int)rintf(b.x * scale));
    atomicAdd(dst + 5, (int)rintf(b.y * scale));
    atomicAdd(dst + 6, (int)rintf(b.z * scale));
    atomicAdd(dst + 7, (int)rintf(b.w * scale));
    if (ch == 0) atomicAdd(&hcnt[c], 1);
  }
  __syncthreads();
  const int slice = blockIdx.x & (NSLICE - 1);
  for (int i = t; i < NCLUST * DDIM; i += 256) {
    int x = cs[i];
    if (x) atomicAdd(&csum_i32[(size_t)slice * NCLUST * DDIM + i], x);
  }
  if (t < NCLUST && hcnt[t]) atomicAdd(&hist8[slice * 128 + t], hcnt[t]);
}

// ---- sim: R14's exact kernel — no-LDS fp8 MFMA GEMM, 16-row blocks,
// 8 waves/SIMD (the only spill-free 8w/SIMD config), dual acc chains ----
#define PUSHQ(av, q)                                                            \
  if ((av) > TAU_L2E) {                                                         \
    int rw = r0 + lhi * 4 + (q);                                                \
    int slot = atomicAdd(&cnt[rw], 1);                                          \
    if (slot < CAP) { lv[rw * CAP + slot] = (av) * LN2; li[rw * CAP + slot] = colv; } \
  }

#define LOADB(dst, gptr)                                                        \
  { dst[0] = *(const uint4*)((gptr) + (size_t)lane * 16);                       \
    dst[1] = *(const uint4*)((gptr) + 1024 + (size_t)lane * 16); }

// consume bb (iter itv) while refilling bb in-place for iter itv+2
#define COMPUTE_REFILL(bb, itv, refbase, dorefill)                              \
  {                                                                             \
    f32x4 acA = {0,0,0,0}, acB = {0,0,0,0};                                     \
    lg2 bs0 = __builtin_bit_cast(lg2, bb[0]);                                   \
    lg2 bs1 = __builtin_bit_cast(lg2, bb[1]);                                   \
    if (dorefill) {                                                             \
      bb[0] = *(const uint4*)((refbase) + (size_t)lane * 16);                   \
      bb[1] = *(const uint4*)((refbase) + 1024 + (size_t)lane * 16);            \
    }                                                                           \
    acA = __builtin_amdgcn_mfma_f32_16x16x32_fp8_fp8(afr[0][0], bs0[0], acA, 0, 0, 0); \
    acB = __builtin_amdgcn_mfma_f32_16x16x32_fp8_fp8(afr[1][0], bs1[0], acB, 0, 0, 0); \
    acA = __builtin_amdgcn_mfma_f32_16x16x32_fp8_fp8(afr[0][1], bs0[1], acA, 0, 0, 0); \
    acB = __builtin_amdgcn_mfma_f32_16x16x32_fp8_fp8(afr[1][1], bs1[1], acB, 0, 0, 0); \
    f32x4 a = acA + acB;                                                        \
    se.x += __builtin_amdgcn_exp2f(a.x);                                        \
    se.y += __builtin_amdgcn_exp2f(a.y);                                        \
    se.z += __builtin_amdgcn_exp2f(a.z);                                        \
    se.w += __builtin_amdgcn_exp2f(a.w);                                        \
    float mx = fmaxf(fmaxf(a.x, a.y), fmaxf(a.z, a.w));                         \
    if (mx > TAU_L2E) {                                                         \
      const int colv = chunk * CHUNK_COLS + (itv) * 64 + w * 16 + l15;          \
      PUSHQ(a.x, 0) PUSHQ(a.y, 1) PUSHQ(a.z, 2) PUSHQ(a.w, 3)                   \
    }                                                                           \
  }

__global__ __launch_bounds__(256, 8) void sim_kernel(
    const char* __restrict__ wsf2, const char* __restrict__ wsg2,
    float* __restrict__ p_se, float* __restrict__ lv, int* __restrict__ li,
    int* __restrict__ cnt) {
  __shared__ float sered[4][ROWSB];
  const int t = threadIdx.x, lane = t & 63, w = t >> 6;
  const int l15 = lane & 15, lhi = lane >> 4;
  const int chunk = blockIdx.x;          // 0..15 (chunk%8 -> XCD pinned)
  const int r0 = blockIdx.y * ROWSB;

  // hoist A fragments: 16 f-rows x 128 K in regs (8 VGPR)
  // afr[sp] = K slices {2sp, 2sp+1} (i64 each): afr[0] pairs bs0, afr[1] pairs bs1
  const char* fbase = wsf2 + (size_t)(r0 >> 4) * GRPB;
  lg2 afr[2];
  #pragma unroll
  for (int sp = 0; sp < 2; ++sp)
    afr[sp] = __builtin_bit_cast(lg2,
      *(const uint4*)(fbase + sp * 1024 + (size_t)lane * 16));

  f32x4 se = {0.f, 0.f, 0.f, 0.f};

  // wave w's 16-col group for iter it lives at (it*4 + w)*GRPB
  const char* gb = wsg2 + (size_t)(chunk * (CHUNK_COLS / 16) + w) * GRPB;
  uint4 b0[2], b1[2];
  LOADB(b0, gb)                          // it+0
  LOADB(b1, gb + 8192)                   // it+1
  for (int it = 0; it < ITERS; it += 2) {
    COMPUTE_REFILL(b0, it,     gb + 2 * 8192, it + 2 < ITERS)   // refill -> it+2
    COMPUTE_REFILL(b1, it + 1, gb + 3 * 8192, it + 3 < ITERS)   // refill -> it+3
    gb += 2 * 8192;
  }

  #pragma unroll
  for (int q = 0; q < 4; ++q) {
    float s = se[q];
    s += __shfl_xor(s, 1); s += __shfl_xor(s, 2);
    s += __shfl_xor(s, 4); s += __shfl_xor(s, 8);
    if (l15 == 0) sered[w][lhi * 4 + q] = s;
  }
  __syncthreads();
  if (t < ROWSB) {
    float s = sered[0][t] + sered[1][t] + sered[2][t] + sered[3][t];
    p_se[(size_t)(r0 + t) * NSPLIT + chunk] = s;
  }
}

// ---- merge (+inline fallback): per-row se, cluster dot, exact top-10 ----
__global__ __launch_bounds__(256) void merge_kernel(
    const float* __restrict__ f, const int* __restrict__ fclust,
    const int* __restrict__ gclust, const float* __restrict__ inv_fT,
    const float* __restrict__ p_se, const int* __restrict__ csum_i32,
    const int* __restrict__ hist8, const float* __restrict__ lv,
    const int* __restrict__ li, const int* __restrict__ cnt,
    const char* __restrict__ wsf2, const char* __restrict__ wsg2,
    float* __restrict__ rowv) {
  const int lane = threadIdx.x & 63, w = threadIdx.x >> 6;
  const int r = blockIdx.x * 4 + w;

  float sev = (lane < NSPLIT) ? p_se[(size_t)r * NSPLIT + lane] : 0.f;
  sev += __shfl_xor(sev, 8); sev += __shfl_xor(sev, 4);
  sev += __shfl_xor(sev, 2); sev += __shfl_xor(sev, 1);
  sev = __shfl(sev, 0);

  int rc = fclust[r];
  float2 fv = ((const float2*)(f + (size_t)r * DDIM))[lane];
  float sc = inv_fT[r];
  int ia = 0, ib = 0, hc = 0;
  #pragma unroll
  for (int s = 0; s < NSLICE; ++s) {
    ia += csum_i32[(size_t)s * NCLUST * DDIM + rc * DDIM + 2 * lane];
    ib += csum_i32[(size_t)s * NCLUST * DDIM + rc * DDIM + 2 * lane + 1];
    hc += hist8[s * 128 + rc];
  }
  float dt = fv.x * sc * (ia * INV_CSC) + fv.y * sc * (ib * INV_CSC);
  #pragma unroll
  for (int m = 32; m; m >>= 1) dt += __shfl_xor(dt, m);
  dt = __shfl(dt, 0);

  float Cc = (float)hc;
  int n = cnt[r];
  bool bad = (n < TOPK) || (n > CAP);
  float S10 = 0.f, C10 = 0.f;
  if (!bad) {
    u64 k0 = 0, k1 = 0, k2 = 0, k3 = 0;
    int e = lane;
    if (e < n) k0 = mkkey(lv[(size_t)r * CAP + e], li[(size_t)r * CAP + e]);
    e = lane + 64;
    if (e < n) k1 = mkkey(lv[(size_t)r * CAP + e], li[(size_t)r * CAP + e]);
    e = lane + 128;
    if (e < n) k2 = mkkey(lv[(size_t)r * CAP + e], li[(size_t)r * CAP + e]);
    e = lane + 192;
    if (e < n) k3 = mkkey(lv[(size_t)r * CAP + e], li[(size_t)r * CAP + e]);
    for (int it = 0; it < TOPK; ++it) {
      u64 best = umax64(umax64(k0, k1), umax64(k2, k3));
      #pragma unroll
      for (int m = 32; m; m >>= 1) best = umax64(best, __shfl_xor(best, m));
      float val = fmono_inv((unsigned)(best >> 32));
      int col = (int)(~(unsigned)(best & 0xFFFFFFFFull));
      int gc = gclust[col];
      if (gc != rc) { S10 += val; C10 += 1.f; }
      if (k0 == best) k0 = 0;
      if (k1 == best) k1 = 0;
      if (k2 == best) k2 = 0;
      if (k3 == best) k3 = 0;
    }
  } else {
    // inline fallback: exact top-10 via full fp8 recompute (rare; correctness net)
    uint4 fr[8];
    #pragma unroll
    for (int pc = 0; pc < 8; ++pc)
      fr[pc] = *(const uint4*)(wsf2 + (size_t)(r >> 4) * GRPB + (pc >> 2) * 1024
                               + (pc & 3) * 256 + (r & 15) * 16);
    u64 tk[TOPK];
    #pragma unroll
    for (int i = 0; i < TOPK; ++i) tk[i] = 0;
    for (int col = lane; col < N_GLB; col += 64) {
      const char* gp = wsg2 + (size_t)(col >> 4) * GRPB + (col & 15) * 16;
      float acc = 0.f;
      #pragma unroll
      for (int pc = 0; pc < 8; ++pc) {
        uint4 gv = *(const uint4*)(gp + (pc >> 2) * 1024 + (pc & 3) * 256);
        uint4 fc = fr[pc];
        #pragma unroll
        for (int wd = 0; wd < 4; ++wd) {
          unsigned fa = (&fc.x)[wd], ga = (&gv.x)[wd];
          #pragma unroll
          for (int b = 0; b < 4; ++b)
            acc += fp8d((fa >> (8 * b)) & 0xFFu) * fp8d((ga >> (8 * b)) & 0xFFu);
        }
      }
      u64 key = mkkey(acc, col);   // acc in log2e units; monotonic ordering ok
      if (key > tk[0]) {
        u64 cur = key;
        #pragma unroll
        for (int i = 0; i < TOPK - 1; ++i) {
          u64 nxt = tk[i + 1];
          u64 lo = cur < nxt ? cur : nxt;
          u64 hi = cur < nxt ? nxt : cur;
          tk[i] = lo; cur = hi;
        }
        tk[TOPK - 1] = cur;
      }
    }
    for (int it = 0; it < TOPK; ++it) {
      u64 best = tk[TOPK - 1];
      #pragma unroll
      for (int m = 32; m; m >>= 1) best = umax64(best, __shfl_xor(best, m));
      float val = fmono_inv((unsigned)(best >> 32)) * LN2;
      int col = (int)(~(unsigned)(best & 0xFFFFFFFFull));
      if (gclust[col] != rc) { S10 += val; C10 += 1.f; }
      if (tk[TOPK - 1] == best) {
        #pragma unroll
        for (int i = TOPK - 1; i > 0; --i) tk[i] = tk[i - 1];
        tk[0] = 0;
      }
    }
  }
  if (lane == 0) {
    float L = logf(sev + 1e-12f);
    float C = Cc + C10;
    rowv[r] = (dt + S10 - C * L) / (C + 1e-12f);
  }
}

__global__ void final_kernel(const float* __restrict__ rowv, float* __restrict__ out) {
  __shared__ float sm[256];
  int t = threadIdx.x;
  float s = 0.f;
  for (int i = t; i < B_ROWS; i += 256) s += rowv[i];
  sm[t] = s;
  __syncthreads();
  for (int o = 128; o; o >>= 1) { if (t < o) sm[t] += sm[t + o]; __syncthreads(); }
  if (t == 0) out[0] = -(sm[0] / (float)B_ROWS);
}

extern "C" void kernel_launch(void* const* d_in, const int* in_sizes, int n_in,
                              void* d_out, int out_size, void* d_ws, size_t ws_size,
                              hipStream_t stream) {
  const float* f  = (const float*)d_in[0];
  const int*   fc = (const int*)  d_in[1];
  const float* g  = (const float*)d_in[2];
  const int*   gc = (const int*)  d_in[3];
  float* out = (float*)d_out;

  char* ws = (char*)d_ws;
  char*  wsf2    = ws;                          // 256 KB fp8 f
  char*  wsg2    = ws + 262144;                 // 8 MB fp8 g -> 8650752
  float* inv_fT  = (float*)(ws + 8650752);      // 8 KB  -> 8658944
  float* inv_g   = (float*)(ws + 8658944);      // 256 KB -> 8921088
  float* p_se    = (float*)(ws + 8921088);      // 128 KB -> 9052160
  // zero region [9052160, 9474048): csum 409600 + hist8 4096 + cnt 8192
  int*   csum_i32= (int*)  (ws + 9052160);      // 409600 -> 9461760
  int*   hist8   = (int*)  (ws + 9461760);      // 4096   -> 9465856
  int*   cnt     = (int*)  (ws + 9465856);      // 8192   -> 9474048
  unsigned* zbase= (unsigned*)(ws + 9052160);   // ZWORDS = 105472 u32 words
  float* lv      = (float*)(ws + 9474048);      // 2 MB -> 11571200
  int*   li      = (int*)  (ws + 11571200);     // 2 MB -> 13668352
  float* rowv    = (float*)(ws + 13668352);     // 8 KB (total ~13.7 MB)

  prep_kernel<<<(B_ROWS + N_GLB) / 16, 256, 0, stream>>>(f, g, wsf2, wsg2,
                                                         inv_fT, inv_g, zbase);

  csum2_kernel<<<N_GLB / 256, 256, 0, stream>>>(g, gc, inv_g, csum_i32, hist8);

  dim3 grid(NSPLIT, B_ROWS / ROWSB);   // 16 x 128 = 2048 blocks (8/CU, 32 waves/CU)
  sim_kernel<<<grid, 256, 0, stream>>>(wsf2, wsg2, p_se, lv, li, cnt);

  merge_kernel<<<B_ROWS / 4, 256, 0, stream>>>(f, fc, gc, inv_fT, p_se, csum_i32,
                                               hist8, lv, li, cnt, wsf2, wsg2, rowv);
  final_kernel<<<1, 256, 0, stream>>>(rowv, out);
}